// Round 5
// baseline (272.913 us; speedup 1.0000x reference)
//
#include <hip/hip_runtime.h>

#define NPTS 32768
#define BLOCK 256
#define SPT 16                            // source points per thread
#define NSLICE 64                         // target slices per direction
#define SLICE_PTS (NPTS / NSLICE)         // 512
#define SRC_PER_BLOCK (BLOCK * SPT)       // 4096
#define SRC_CHUNKS (NPTS / SRC_PER_BLOCK) // 8
#define GRID (2 * SRC_CHUNKS * NSLICE)    // 1024 blocks -> 4 blocks/CU, 16 waves/CU
#define SENTINEL 0x7F7F7F7Fu              // == 3.39e38f; memset pattern 0x7F
#define LASTVAL (SENTINEL + (unsigned)GRID - 1u)

// Pass 1: block = (dir, source-chunk of 4096, target-slice of 512).
// min_t |s-t|^2 = |s|^2 - 2 * max_t (s.t - |t|^2/2); qh = -|t|^2/2 staged in LDS.
// Per j-step: 2 broadcast ds_read_b128 feed 16 pts x (6 fma + 1 max3) = 112 VALU.
// FUSED: last block to finish reduces the 256 KB mins array and writes the loss.
template <bool FUSED>
__global__ __launch_bounds__(BLOCK, 4)
void chamfer_pass1(const float* __restrict__ pred,
                   const float* __restrict__ targ,
                   unsigned int* __restrict__ mins,
                   unsigned int* __restrict__ counter,
                   float* __restrict__ out) {
    __shared__ float4 sh[SLICE_PTS];

    int b = blockIdx.x;
    int dir = b >> 9;              // 0: pred->target, 1: target->pred
    int rem = b & 511;
    int slice = rem >> 3;          // 0..63
    int chunk = rem & 7;           // 0..7

    const float* src = dir ? targ : pred;
    const float* tgt = dir ? pred : targ;
    unsigned int* outm = mins + dir * NPTS;

    // stage the target slice as {x, y, z, -|t|^2/2}
    int slice_base = slice * SLICE_PTS;
    #pragma unroll
    for (int k = 0; k < SLICE_PTS / BLOCK; ++k) {
        int j = threadIdx.x + k * BLOCK;
        int g = slice_base + j;
        float x = tgt[3*g+0], y = tgt[3*g+1], z = tgt[3*g+2];
        sh[j] = make_float4(x, y, z, -0.5f * (x*x + y*y + z*z));
    }

    // 16 source points in registers
    float sx[SPT], sy[SPT], sz[SPT], m[SPT];
    int i_base = chunk * SRC_PER_BLOCK + threadIdx.x;
    #pragma unroll
    for (int p = 0; p < SPT; ++p) {
        int i = i_base + p * BLOCK;
        sx[p] = src[3*i+0]; sy[p] = src[3*i+1]; sz[p] = src[3*i+2];
        m[p] = -3.4e38f;
    }
    __syncthreads();

    #pragma unroll 8
    for (int j = 0; j < SLICE_PTS; j += 2) {
        float4 ta = sh[j];
        float4 tb = sh[j+1];
        #pragma unroll
        for (int p = 0; p < SPT; ++p) {
            float ra = fmaf(sx[p], ta.x, fmaf(sy[p], ta.y, fmaf(sz[p], ta.z, ta.w)));
            float rb = fmaf(sx[p], tb.x, fmaf(sy[p], tb.y, fmaf(sz[p], tb.z, tb.w)));
            m[p] = fmaxf(fmaxf(ra, rb), m[p]);   // -> v_max3_f32
        }
    }

    #pragma unroll
    for (int p = 0; p < SPT; ++p) {
        int i = i_base + p * BLOCK;
        float q = fmaf(sx[p], sx[p], fmaf(sy[p], sy[p], sz[p]*sz[p]));
        float d = fmaxf(fmaf(-2.0f, m[p], q), 0.0f);  // exact distance >= 0
        atomicMin(&outm[i], __float_as_uint(d));      // non-neg float: uint cmp ok
    }

    if (!FUSED) return;

    // ---- fused finalization: last block reduces ----
    __threadfence();   // release our mins updates device-wide
    __shared__ unsigned int is_last;
    if (threadIdx.x == 0)
        is_last = (atomicAdd(counter, 1u) == LASTVAL) ? 1u : 0u;
    __syncthreads();
    if (is_last) {
        __threadfence();   // acquire side
        float sum = 0.0f;
        for (int i = threadIdx.x; i < 2 * NPTS; i += BLOCK) {
            unsigned int u = __hip_atomic_load(&mins[i], __ATOMIC_RELAXED,
                                               __HIP_MEMORY_SCOPE_AGENT);
            sum += __uint_as_float(u);
        }
        #pragma unroll
        for (int off = 32; off > 0; off >>= 1)
            sum += __shfl_down(sum, off, 64);
        __shared__ float wsum[4];
        int lane = threadIdx.x & 63, wave = threadIdx.x >> 6;
        if (lane == 0) wsum[wave] = sum;
        __syncthreads();
        if (threadIdx.x == 0)
            out[0] = (wsum[0] + wsum[1] + wsum[2] + wsum[3]) * (1.0f / NPTS);
    }
}

// Fallback pass 2 (only used if ws_size can't hold the counter word).
__global__ __launch_bounds__(256)
void chamfer_pass2(const unsigned int* __restrict__ mins,
                   float* __restrict__ out) {
    float sum = 0.0f;
    for (int i = blockIdx.x * blockDim.x + threadIdx.x; i < 2 * NPTS;
         i += gridDim.x * blockDim.x)
        sum += __uint_as_float(mins[i]);
    #pragma unroll
    for (int off = 32; off > 0; off >>= 1)
        sum += __shfl_down(sum, off, 64);
    __shared__ float wsum[4];
    int lane = threadIdx.x & 63, wave = threadIdx.x >> 6;
    if (lane == 0) wsum[wave] = sum;
    __syncthreads();
    if (threadIdx.x == 0)
        atomicAdd(out, (wsum[0] + wsum[1] + wsum[2] + wsum[3]) * (1.0f / NPTS));
}

extern "C" void kernel_launch(void* const* d_in, const int* in_sizes, int n_in,
                              void* d_out, int out_size, void* d_ws, size_t ws_size,
                              hipStream_t stream) {
    const float* pred = (const float*)d_in[0];
    const float* targ = (const float*)d_in[1];
    float* out = (float*)d_out;
    unsigned int* mins = (unsigned int*)d_ws;
    unsigned int* counter = mins + 2 * NPTS;

    if (ws_size >= (size_t)(2 * NPTS + 1) * sizeof(unsigned int)) {
        // mins sentinel + counter sentinel in ONE memset (0x7F7F7F7F each)
        hipMemsetAsync(d_ws, 0x7F, (2 * NPTS + 1) * sizeof(unsigned int), stream);
        chamfer_pass1<true><<<GRID, BLOCK, 0, stream>>>(pred, targ, mins, counter, out);
    } else {
        hipMemsetAsync(d_ws, 0x7F, 2 * NPTS * sizeof(unsigned int), stream);
        hipMemsetAsync(d_out, 0, sizeof(float), stream);
        chamfer_pass1<false><<<GRID, BLOCK, 0, stream>>>(pred, targ, mins, counter, out);
        chamfer_pass2<<<64, 256, 0, stream>>>(mins, out);
    }
}